// Round 4
// baseline (1005.444 us; speedup 1.0000x reference)
//
#include <hip/hip_runtime.h>
#include <hip/hip_fp16.h>

#define N_NODES 100000
#define N_EDGES 1600000
#define INP 16
#define EMB 32
#define ATTN 32
#define D0 48
#define RREL 200
#define NB 4
#define GAMMA_C 10.0f

#define SCAN_T 256
#define SCAN_I 4
#define SCAN_TILE 1024
#define NTILES ((N_NODES + SCAN_TILE - 1) / SCAN_TILE)   // 98

__device__ inline unsigned pack_h2(float a, float b) {
  __half2 h = __floats2half2_rn(a, b);
  return *reinterpret_cast<unsigned*>(&h);
}

// ---------------- node prep: 4 threads/node. thread j: computes a1/a2 channels [8j,8j+8)
// and writes h0 slice [12j, 12j+12).
__global__ __launch_bounds__(256) void k_node_prep(
    const float* __restrict__ feat, const int* __restrict__ node_ids,
    const float* __restrict__ embed,
    const float* __restrict__ A1w, const float* __restrict__ A1b,
    const float* __restrict__ A2w, const float* __restrict__ A2b,
    float* __restrict__ h0, float* __restrict__ a1, float* __restrict__ a2) {
  int gid = blockIdx.x * blockDim.x + threadIdx.x;
  int n = gid >> 2, j = gid & 3;
  if (n >= N_NODES) return;
  float h[D0];
  const float4* f4 = reinterpret_cast<const float4*>(feat + (size_t)n * INP);
  #pragma unroll
  for (int i = 0; i < INP / 4; ++i) {
    float4 v = f4[i];
    h[4*i+0] = v.x; h[4*i+1] = v.y; h[4*i+2] = v.z; h[4*i+3] = v.w;
  }
  int nid = node_ids[n];
  const float4* e4 = reinterpret_cast<const float4*>(embed + (size_t)nid * EMB);
  #pragma unroll
  for (int i = 0; i < EMB / 4; ++i) {
    float4 v = e4[i];
    h[INP+4*i+0] = v.x; h[INP+4*i+1] = v.y; h[INP+4*i+2] = v.z; h[INP+4*i+3] = v.w;
  }
  // h0 slice: 12 floats = 3 float4
  float4* h04 = reinterpret_cast<float4*>(h0 + (size_t)n * D0 + j * 12);
  #pragma unroll
  for (int i = 0; i < 3; ++i)
    h04[i] = make_float4(h[j*12+4*i], h[j*12+4*i+1], h[j*12+4*i+2], h[j*12+4*i+3]);
  // a1/a2 channels [8j, 8j+8)
  float o1[8], o2[8];
  #pragma unroll
  for (int o = 0; o < 8; ++o) { o1[o] = A1b[8*j+o]; o2[o] = A2b[8*j+o]; }
  for (int i = 0; i < D0; ++i) {
    float hv = h[i];
    #pragma unroll
    for (int o = 0; o < 8; ++o) {
      o1[o] += hv * A1w[(8*j+o) * D0 + i];
      o2[o] += hv * A2w[(8*j+o) * D0 + i];
    }
  }
  float4* p1 = reinterpret_cast<float4*>(a1 + (size_t)n * ATTN + 8*j);
  p1[0] = make_float4(o1[0], o1[1], o1[2], o1[3]);
  p1[1] = make_float4(o1[4], o1[5], o1[6], o1[7]);
  float4* p2 = reinterpret_cast<float4*>(a2 + (size_t)n * ATTN + 8*j);
  p2[0] = make_float4(o2[0], o2[1], o2[2], o2[3]);
  p2[1] = make_float4(o2[4], o2[5], o2[6], o2[7]);
}

// ---------------- CSR build
__global__ __launch_bounds__(256) void k_hist(const int* __restrict__ dst, int* __restrict__ cnt) {
  int e = blockIdx.x * blockDim.x + threadIdx.x;
  if (e >= N_EDGES) return;
  atomicAdd(&cnt[dst[e]], 1);
}

__global__ __launch_bounds__(SCAN_T) void k_scan1(const int* __restrict__ cnt,
                                                  int* __restrict__ excl, int* __restrict__ bsum) {
  __shared__ int sd[SCAN_T];
  int blk = blockIdx.x, tid = threadIdx.x;
  int base = blk * SCAN_TILE + tid * SCAN_I;
  int v[SCAN_I]; int s = 0;
  #pragma unroll
  for (int i = 0; i < SCAN_I; ++i) { int idx = base + i; v[i] = (idx < N_NODES) ? cnt[idx] : 0; s += v[i]; }
  sd[tid] = s; __syncthreads();
  for (int off = 1; off < SCAN_T; off <<= 1) {
    int t = (tid >= off) ? sd[tid - off] : 0;
    __syncthreads();
    sd[tid] += t;
    __syncthreads();
  }
  int run = sd[tid] - s;
  #pragma unroll
  for (int i = 0; i < SCAN_I; ++i) { int idx = base + i; if (idx < N_NODES) excl[idx] = run; run += v[i]; }
  if (tid == SCAN_T - 1) bsum[blk] = sd[tid];
}

__global__ __launch_bounds__(128) void k_scan2(int* __restrict__ bsum) {
  __shared__ int sd[128];
  int tid = threadIdx.x;
  int v = (tid < NTILES) ? bsum[tid] : 0;
  sd[tid] = v; __syncthreads();
  for (int off = 1; off < 128; off <<= 1) {
    int t = (tid >= off) ? sd[tid - off] : 0;
    __syncthreads();
    sd[tid] += t;
    __syncthreads();
  }
  if (tid < NTILES) bsum[tid] = sd[tid] - v;
}

__global__ __launch_bounds__(256) void k_scan3(int* __restrict__ row_start, int* __restrict__ cursor,
                                               const int* __restrict__ bsum) {
  int i = blockIdx.x * blockDim.x + threadIdx.x;
  if (i < N_NODES) {
    int v = row_start[i] + bsum[i / SCAN_TILE];
    row_start[i] = v; cursor[i] = v;
  }
  if (i == 0) row_start[N_NODES] = N_EDGES;
}

__global__ __launch_bounds__(256) void k_scatter(
    const int* __restrict__ src, const int* __restrict__ dst, const int* __restrict__ typ,
    int* __restrict__ cursor, int2* __restrict__ s_st) {
  int e = blockIdx.x * blockDim.x + threadIdx.x;
  if (e >= N_EDGES) return;
  int d = dst[e];
  int pos = atomicAdd(&cursor[d], 1);
  s_st[pos] = make_int2(src[e], typ[e]);
}

// ---------------- per-node layer: 4 threads/node. thread j owns channels [8j,8j+8) for
// all 4 bases -> writes 64 B contiguous of hb_h ([n][c][b] fp16 layout) + 32 B of selfbuf.
template <int DIN>
__global__ __launch_bounds__(256) void k_node_layer(
    const float* __restrict__ hin, const float* __restrict__ bases,
    const float* __restrict__ sloop, const float* __restrict__ bias,
    unsigned* __restrict__ hb_h, float* __restrict__ selfbuf) {
  int gid = blockIdx.x * blockDim.x + threadIdx.x;
  int n = gid >> 2, j = gid & 3;
  if (n >= N_NODES) return;
  float h[DIN];
  const float4* h4 = reinterpret_cast<const float4*>(hin + (size_t)n * DIN);
  #pragma unroll
  for (int i = 0; i < DIN / 4; ++i) {
    float4 v = h4[i];
    h[4*i+0] = v.x; h[4*i+1] = v.y; h[4*i+2] = v.z; h[4*i+3] = v.w;
  }
  float acc[NB][8];
  #pragma unroll
  for (int b = 0; b < NB; ++b)
    #pragma unroll
    for (int c = 0; c < 8; ++c) acc[b][c] = 0.f;
  float s[8];
  #pragma unroll
  for (int c = 0; c < 8; ++c) s[c] = bias[8*j+c];
  for (int i = 0; i < DIN; ++i) {
    float hv = h[i];
    #pragma unroll
    for (int b = 0; b < NB; ++b) {
      const float* br = bases + ((size_t)(b * DIN) + i) * EMB + 8*j;
      #pragma unroll
      for (int c = 0; c < 8; ++c) acc[b][c] += hv * br[c];
    }
    const float* sr = sloop + (size_t)i * EMB + 8*j;
    #pragma unroll
    for (int c = 0; c < 8; ++c) s[c] += hv * sr[c];
  }
  // pack: halves position c*4+b ; thread covers uints [n*64 + j*16, +16)
  uint4 pk[4];
  #pragma unroll
  for (int c = 0; c < 8; c += 2) {
    uint4 v;
    v.x = pack_h2(acc[0][c],   acc[1][c]);
    v.y = pack_h2(acc[2][c],   acc[3][c]);
    v.z = pack_h2(acc[0][c+1], acc[1][c+1]);
    v.w = pack_h2(acc[2][c+1], acc[3][c+1]);
    pk[c >> 1] = v;
  }
  uint4* orow = reinterpret_cast<uint4*>(hb_h + (size_t)n * 64 + j * 16);
  #pragma unroll
  for (int q = 0; q < 4; ++q) orow[q] = pk[q];
  float4* ob = reinterpret_cast<float4*>(selfbuf + (size_t)n * EMB + 8*j);
  ob[0] = make_float4(s[0], s[1], s[2], s[3]);
  ob[1] = make_float4(s[4], s[5], s[6], s[7]);
}

// ---------------- segmented aggregation: one wave per dst node; optionally fused alpha
template <bool FUSED>
__global__ __launch_bounds__(256) void k_edge_seg(
    const int* __restrict__ row_start,
    const int2* __restrict__ s_st, float* __restrict__ s_alpha,
    const float* __restrict__ a1, const float* __restrict__ a2,
    const float* __restrict__ rel,
    const float* __restrict__ wcomp, const uint2* __restrict__ hb_h,
    const float* __restrict__ selfbuf, float* __restrict__ outp) {
  int wave = (blockIdx.x * blockDim.x + threadIdx.x) >> 6;
  int lane = threadIdx.x & 63;
  if (wave >= N_NODES) return;
  int beg = row_start[wave], end = row_start[wave + 1];
  int half = lane >> 5, c = lane & 31;
  float a2v = 0.f;
  if (FUSED) a2v = a2[(size_t)wave * ATTN + c];
  float acc = 0.f;
  for (int e = beg + half; e < end; e += 2) {
    int2 st = s_st[e];
    float a;
    if (FUSED) {
      float dx = a1[(size_t)st.x * ATTN + c] + rel[(size_t)st.y * ATTN + c] - a2v;
      float ss = dx * dx;
      #pragma unroll
      for (int m = 1; m <= 16; m <<= 1) ss += __shfl_xor(ss, m);
      float nrm = sqrtf(ss + 1e-12f);
      a = 1.f / (1.f + __expf(nrm - GAMMA_C));
      if (c == 0) s_alpha[e] = a;
    } else {
      a = s_alpha[e];
    }
    float4 w = *reinterpret_cast<const float4*>(wcomp + (size_t)st.y * NB);
    uint2 v = hb_h[(size_t)st.x * EMB + c];
    __half2 h01 = *reinterpret_cast<__half2*>(&v.x);
    __half2 h23 = *reinterpret_cast<__half2*>(&v.y);
    float2 f01 = __half22float2(h01);
    float2 f23 = __half22float2(h23);
    acc += a * (w.x * f01.x + w.y * f01.y + w.z * f23.x + w.w * f23.y);
  }
  acc += __shfl(acc, lane ^ 32);
  if (lane < 32) {
    size_t o = (size_t)wave * EMB + c;
    outp[o] = fmaxf(selfbuf[o] + acc, 0.f);
  }
}

extern "C" void kernel_launch(void* const* d_in, const int* in_sizes, int n_in,
                              void* d_out, int out_size, void* d_ws, size_t ws_size,
                              hipStream_t stream) {
  const float* feat     = (const float*)d_in[0];
  const int*   node_ids = (const int*)d_in[1];
  const int*   esrc     = (const int*)d_in[2];
  const int*   edst     = (const int*)d_in[3];
  const int*   etyp     = (const int*)d_in[4];
  const float* embed    = (const float*)d_in[5];
  const float* attn_rel = (const float*)d_in[6];
  const float* A1w = (const float*)d_in[7];
  const float* A1b = (const float*)d_in[8];
  const float* A2w = (const float*)d_in[9];
  const float* A2b = (const float*)d_in[10];
  const float* bases0 = (const float*)d_in[11];
  const float* wcomp0 = (const float*)d_in[12];
  const float* sloop0 = (const float*)d_in[13];
  const float* bias0  = (const float*)d_in[14];
  const float* bases1 = (const float*)d_in[15];
  const float* wcomp1 = (const float*)d_in[16];
  const float* sloop1 = (const float*)d_in[17];
  const float* bias1  = (const float*)d_in[18];
  const float* bases2 = (const float*)d_in[19];
  const float* wcomp2 = (const float*)d_in[20];
  const float* sloop2 = (const float*)d_in[21];
  const float* bias2  = (const float*)d_in[22];

  float* ws = (float*)d_ws;
  // [0, 4.8M)        h0 (dead after L0 node layer) ; s_alpha aliases [0, 1.6M)
  // [4.8M, 8.0M)     s_st (int2 x E)
  // [8.0M, 11.2M)    a1
  // [11.2M, 14.4M)   a2
  // [14.4M, 20.8M)   HBh (N*128 halves = 25.6 MB)
  // [20.8M, 24.0M)   selfbuf
  // [24.0M, ...)     CSR metadata
  float*    h0      = ws;
  float*    s_alpha = ws;
  int2*     s_st    = (int2*)(ws + 4800000);
  float*    a1      = ws + 8000000;
  float*    a2      = ws + 11200000;
  unsigned* HBh     = (unsigned*)(ws + 14400000);
  float*    selfbuf = ws + 20800000;
  int* counts    = (int*)(ws + 24000000);
  int* row_start = (int*)(ws + 24100000);
  int* cursor    = (int*)(ws + 24200002);
  int* bsum      = (int*)(ws + 24300002);
  float* out = (float*)d_out;

  dim3 blk(256);
  int nb_n4 = (N_NODES * 4 + 255) / 256;    // 4 threads per node
  int nb_e  = (N_EDGES + 255) / 256;
  int nb_n  = (N_NODES + 255) / 256;
  int nb_w  = (N_NODES * 64) / 256;

  k_node_prep<<<nb_n4, blk, 0, stream>>>(feat, node_ids, embed, A1w, A1b, A2w, A2b, h0, a1, a2);

  hipMemsetAsync(counts, 0, N_NODES * sizeof(int), stream);
  k_hist<<<nb_e, blk, 0, stream>>>(edst, counts);
  k_scan1<<<NTILES, SCAN_T, 0, stream>>>(counts, row_start, bsum);
  k_scan2<<<1, 128, 0, stream>>>(bsum);
  k_scan3<<<nb_n, blk, 0, stream>>>(row_start, cursor, bsum);
  k_scatter<<<nb_e, blk, 0, stream>>>(esrc, edst, etyp, cursor, s_st);

  // layer 0: node compute (reads h0), then fused alpha+aggregate (h0 dead -> s_alpha alias OK)
  k_node_layer<D0><<<nb_n4, blk, 0, stream>>>(h0, bases0, sloop0, bias0, HBh, selfbuf);
  k_edge_seg<true><<<nb_w, blk, 0, stream>>>(row_start, s_st, s_alpha, a1, a2, attn_rel,
                                             wcomp0, (const uint2*)HBh, selfbuf, selfbuf);

  // layer 1
  k_node_layer<EMB><<<nb_n4, blk, 0, stream>>>(selfbuf, bases1, sloop1, bias1, HBh, selfbuf);
  k_edge_seg<false><<<nb_w, blk, 0, stream>>>(row_start, s_st, s_alpha, a1, a2, attn_rel,
                                              wcomp1, (const uint2*)HBh, selfbuf, selfbuf);

  // layer 2 -> d_out
  k_node_layer<EMB><<<nb_n4, blk, 0, stream>>>(selfbuf, bases2, sloop2, bias2, HBh, selfbuf);
  k_edge_seg<false><<<nb_w, blk, 0, stream>>>(row_start, s_st, s_alpha, a1, a2, attn_rel,
                                              wcomp2, (const uint2*)HBh, selfbuf, out);
}